// Round 1
// baseline (279.636 us; speedup 1.0000x reference)
//
#include <hip/hip_runtime.h>
#include <hip/hip_bf16.h>
#include <math.h>

// Problem dims
#define BATCH 8192
#define INF   1024
#define LEAFW 256
#define OUTF  1024
#define NLEAF 16
#define NNODE 15
#define NTOT  4096      // NLEAF * LEAFW
#define KEXT  4160      // 4096 + 64 (mixture @ B2 folded into GEMM2's K)

typedef __bf16 bf16;
typedef __bf16 bf16x8 __attribute__((ext_vector_type(8)));
typedef float  f32x4  __attribute__((ext_vector_type(4)));

// GEMM tile config (m97-style: 128x128 tile, BK=64, 4 waves of 4x4 16x16x32 MFMA)
#define BM 128
#define BN 128
#define BK 64

// ---------------------------------------------------------------------------
// x fp32 -> bf16 (vectorized: 2x float4 in, one 16B bf16x8 out)
__global__ __launch_bounds__(256) void convert_x_kernel(
    const float4* __restrict__ x, bf16x8* __restrict__ xb) {
  int i = blockIdx.x * blockDim.x + threadIdx.x;   // < BATCH*INF/8
  float4 a = x[2 * i], b = x[2 * i + 1];
  bf16x8 o;
  o[0] = (bf16)a.x; o[1] = (bf16)a.y; o[2] = (bf16)a.z; o[3] = (bf16)a.w;
  o[4] = (bf16)b.x; o[5] = (bf16)b.y; o[6] = (bf16)b.z; o[7] = (bf16)b.w;
  xb[i] = o;
}

// ---------------------------------------------------------------------------
// w1s[l][f][h] (16,1024,256) fp32 -> W1T[l*256+h][f] bf16, ld=1024
__global__ __launch_bounds__(256) void transpose_w1_kernel(
    const float* __restrict__ w1, bf16* __restrict__ W1T) {
  __shared__ float tile[32][33];
  int l  = blockIdx.z;
  int hb = blockIdx.x * 32;
  int fb = blockIdx.y * 32;
  int tx = threadIdx.x, ty = threadIdx.y;  // (32, 8)
  const float* in1 = w1 + (size_t)l * INF * LEAFW;
#pragma unroll
  for (int i = 0; i < 4; ++i)
    tile[ty + 8 * i][tx] = in1[(size_t)(fb + ty + 8 * i) * LEAFW + hb + tx];
  __syncthreads();
#pragma unroll
  for (int i = 0; i < 4; ++i)
    W1T[(size_t)(l * LEAFW + hb + ty + 8 * i) * INF + fb + tx] =
        (bf16)tile[tx][ty + 8 * i];
}

// w2s[l][h][o] (16,256,1024) fp32 -> W2T[o][l*256+h] bf16, ld=KEXT
__global__ __launch_bounds__(256) void transpose_w2_kernel(
    const float* __restrict__ w2, bf16* __restrict__ W2T) {
  __shared__ float tile[32][33];
  int l  = blockIdx.z;
  int ob = blockIdx.x * 32;
  int hb = blockIdx.y * 32;
  int tx = threadIdx.x, ty = threadIdx.y;  // (32, 8)
  const float* in2 = w2 + (size_t)l * LEAFW * OUTF;
#pragma unroll
  for (int i = 0; i < 4; ++i)
    tile[ty + 8 * i][tx] = in2[(size_t)(hb + ty + 8 * i) * OUTF + ob + tx];
  __syncthreads();
#pragma unroll
  for (int i = 0; i < 4; ++i)
    W2T[(size_t)(ob + ty + 8 * i) * KEXT + l * LEAFW + hb + tx] =
        (bf16)tile[tx][ty + 8 * i];
}

// fill W2T cols 4096..4159: first 16 = b2s[l][o] transposed, rest zero
__global__ __launch_bounds__(256) void w2ext_kernel(
    const float* __restrict__ b2s, bf16* __restrict__ W2T) {
  int i = blockIdx.x * blockDim.x + threadIdx.x;  // < 1024*64
  int o = i >> 6, j = i & 63;
  W2T[(size_t)o * KEXT + NTOT + j] =
      (j < NLEAF) ? (bf16)b2s[(size_t)j * OUTF + o] : (bf16)0.f;
}

// ---------------------------------------------------------------------------
// Gating: one wave per row. 15 dot products (fp32, exact), sigmoid, tree
// product -> mg[row][16] fp32; also writes mixture (bf16) into Aact cols
// 4096..4111 and zeros cols 4112..4159.
__global__ __launch_bounds__(256) void gating_kernel(
    const float* __restrict__ x, const float* __restrict__ nw,
    const float* __restrict__ nb, float* __restrict__ mg,
    bf16* __restrict__ Aact) {
  int row  = blockIdx.x * 4 + (threadIdx.x >> 6);
  int lane = threadIdx.x & 63;
  const float* xr = x + (size_t)row * INF;

  float p[NNODE];
#pragma unroll
  for (int j = 0; j < NNODE; ++j) p[j] = 0.f;
  for (int c = 0; c < INF / 64; ++c) {
    float xv = xr[c * 64 + lane];
#pragma unroll
    for (int j = 0; j < NNODE; ++j) p[j] += xv * nw[j * INF + c * 64 + lane];
  }
  // butterfly reduce: every lane ends with the full sum for every node
#pragma unroll
  for (int j = 0; j < NNODE; ++j) {
    float v = p[j];
#pragma unroll
    for (int off = 32; off > 0; off >>= 1) v += __shfl_xor(v, off);
    p[j] = 1.f / (1.f + expf(-(v + nb[j])));   // sigmoid
  }
  // mixture for all 16 leaves (wave-uniform, static indices only)
  float mixv[NLEAF];
#pragma unroll
  for (int L = 0; L < NLEAF; ++L) {
    int n1 = 1 + (L >> 3), n2 = 3 + (L >> 2), n3 = 7 + (L >> 1);
    float m = ((L >> 3) & 1) ? p[0] : (1.f - p[0]);
    m *= ((L >> 2) & 1) ? p[n1] : (1.f - p[n1]);
    m *= ((L >> 1) & 1) ? p[n2] : (1.f - p[n2]);
    m *= (L & 1) ? p[n3] : (1.f - p[n3]);
    mixv[L] = m;
  }
  bf16* arow = Aact + (size_t)row * KEXT + NTOT;
  if (lane == 0) {
#pragma unroll
    for (int L = 0; L < NLEAF; ++L) {
      mg[row * NLEAF + L] = mixv[L];
      arow[L] = (bf16)mixv[L];
    }
  }
  if (lane >= 16) arow[lane] = (bf16)0.f;  // cols 4112..4159
}

// ---------------------------------------------------------------------------
// bf16 MFMA GEMM: C[M][N] = A[M][K] (row-major, lda) @ BT[N][K]^T (row-major,
// ldb). 128x128 tile, BK=64, global_load_lds width-16 staging with XOR chunk
// swizzle (coalesced global reads + conflict-free ds_read_b128).
// EPI=0: v = relu(acc + bias[col]) * mg[row][col>>8], store bf16 to outB.
// EPI=1: store fp32 acc to outF.
template <int EPI>
__global__ __launch_bounds__(256, 2) void gemm_kernel(
    const bf16* __restrict__ A, int lda, const bf16* __restrict__ BT, int ldb,
    int K, const float* __restrict__ bias, const float* __restrict__ mg,
    bf16* __restrict__ outB, int ldob, float* __restrict__ outF, int ldof) {
  __shared__ __align__(16) bf16 As[BM * BK];
  __shared__ __align__(16) bf16 Bs[BN * BK];

  int t    = threadIdx.x;
  int lane = t & 63;
  int w    = t >> 6;
  int bm   = blockIdx.x * BM;
  int bn   = blockIdx.y * BN;
  int wm   = (w >> 1) * 64;
  int wn   = (w & 1) * 64;

  int sr = t >> 3;                       // staging row-within-issue (0..31)
  int sc = t & 7;                        // staging chunk (0..7)
  int gc = ((sc ^ (sr & 7)) << 3);       // swizzled global col offset (elems)

  f32x4 acc[4][4];
#pragma unroll
  for (int i = 0; i < 4; ++i)
#pragma unroll
    for (int j = 0; j < 4; ++j) acc[i][j] = (f32x4){0.f, 0.f, 0.f, 0.f};

  for (int k0 = 0; k0 < K; k0 += BK) {
#pragma unroll
    for (int i = 0; i < 4; ++i) {
      int r = i * 32 + sr;
      __builtin_amdgcn_global_load_lds(
          (const __attribute__((address_space(1))) void*)(
              A + (size_t)(bm + r) * lda + k0 + gc),
          (__attribute__((address_space(3))) void*)((char*)As + i * 4096 +
                                                    t * 16),
          16, 0, 0);
    }
#pragma unroll
    for (int i = 0; i < 4; ++i) {
      int r = i * 32 + sr;
      __builtin_amdgcn_global_load_lds(
          (const __attribute__((address_space(1))) void*)(
              BT + (size_t)(bn + r) * ldb + k0 + gc),
          (__attribute__((address_space(3))) void*)((char*)Bs + i * 4096 +
                                                    t * 16),
          16, 0, 0);
    }
    __syncthreads();

#pragma unroll
    for (int kk = 0; kk < 2; ++kk) {
      int c = (kk * 4 + (lane >> 4)) ^ (lane & 7);  // swizzled chunk
      bf16x8 af[4], bfr[4];
#pragma unroll
      for (int i = 0; i < 4; ++i) {
        int R = wm + i * 16 + (lane & 15);
        af[i] = *reinterpret_cast<const bf16x8*>(&As[R * 64 + c * 8]);
      }
#pragma unroll
      for (int j = 0; j < 4; ++j) {
        int R = wn + j * 16 + (lane & 15);
        bfr[j] = *reinterpret_cast<const bf16x8*>(&Bs[R * 64 + c * 8]);
      }
#pragma unroll
      for (int i = 0; i < 4; ++i)
#pragma unroll
        for (int j = 0; j < 4; ++j)
          acc[i][j] = __builtin_amdgcn_mfma_f32_16x16x32_bf16(
              af[i], bfr[j], acc[i][j], 0, 0, 0);
    }
    __syncthreads();
  }

  // Epilogue. C/D layout (m89-verified): col = lane&15, row = (lane>>4)*4+reg
  int r0 = bm + wm + ((lane >> 4) << 2);
  int c0 = bn + wn + (lane & 15);
  if (EPI == 0) {
    int leaf = (bn + wn) >> 8;  // wave-uniform: 64-col span within 256 block
#pragma unroll
    for (int i = 0; i < 4; ++i) {
#pragma unroll
      for (int r = 0; r < 4; ++r) {
        int row = r0 + i * 16 + r;
        float g = mg[row * NLEAF + leaf];
#pragma unroll
        for (int j = 0; j < 4; ++j) {
          int col = c0 + j * 16;
          float v = acc[i][j][r] + bias[col];
          v = v > 0.f ? v : 0.f;
          outB[(size_t)row * ldob + col] = (bf16)(v * g);
        }
      }
    }
  } else {
#pragma unroll
    for (int i = 0; i < 4; ++i)
#pragma unroll
      for (int r = 0; r < 4; ++r) {
        int row = r0 + i * 16 + r;
#pragma unroll
        for (int j = 0; j < 4; ++j)
          outF[(size_t)row * ldof + (c0 + j * 16)] = acc[i][j][r];
      }
  }
}

// ---------------------------------------------------------------------------
extern "C" void kernel_launch(void* const* d_in, const int* in_sizes, int n_in,
                              void* d_out, int out_size, void* d_ws,
                              size_t ws_size, hipStream_t stream) {
  const float* x   = (const float*)d_in[0];  // [8192][1024]
  const float* nw  = (const float*)d_in[1];  // [15][1024]
  const float* nb  = (const float*)d_in[2];  // [15]
  const float* w1s = (const float*)d_in[3];  // [16][1024][256]
  const float* b1s = (const float*)d_in[4];  // [16][256] -> flat [4096]
  const float* w2s = (const float*)d_in[5];  // [16][256][1024]
  const float* b2s = (const float*)d_in[6];  // [16][1024]
  float* out = (float*)d_out;                // [8192][1024]

  char* ws = (char*)d_ws;
  bf16*  Xbf  = (bf16*)(ws);                  // 16,777,216 B
  bf16*  W1T  = (bf16*)(ws + 16777216);       //  8,388,608 B  [4096][1024]
  bf16*  W2T  = (bf16*)(ws + 25165824);       //  8,519,680 B  [1024][4160]
  float* mg   = (float*)(ws + 33685504);      //    524,288 B  [8192][16]
  bf16*  Aact = (bf16*)(ws + 34209792);       // 68,157,440 B  [8192][4160]

  convert_x_kernel<<<dim3((BATCH * INF / 8) / 256), 256, 0, stream>>>(
      (const float4*)x, (bf16x8*)Xbf);
  transpose_w1_kernel<<<dim3(LEAFW / 32, INF / 32, NLEAF), dim3(32, 8), 0,
                        stream>>>(w1s, W1T);
  transpose_w2_kernel<<<dim3(OUTF / 32, LEAFW / 32, NLEAF), dim3(32, 8), 0,
                        stream>>>(w2s, W2T);
  w2ext_kernel<<<dim3(OUTF * 64 / 256), 256, 0, stream>>>(b2s, W2T);
  gating_kernel<<<dim3(BATCH / 4), 256, 0, stream>>>(x, nw, nb, mg, Aact);

  // GEMM1: Aact[:, :4096] = relu(Xbf @ W1T^T + b1) * mixture
  gemm_kernel<0><<<dim3(BATCH / BM, NTOT / BN), 256, 0, stream>>>(
      Xbf, INF, W1T, INF, INF, b1s, mg, Aact, KEXT, nullptr, 0);
  // GEMM2: out = Aact @ W2T^T   (K = 4160 includes mixture @ B2 term)
  gemm_kernel<1><<<dim3(BATCH / BM, OUTF / BN), 256, 0, stream>>>(
      Aact, KEXT, W2T, KEXT, KEXT, nullptr, nullptr, nullptr, 0, out, OUTF);
}

// Round 2
// 267.644 us; speedup vs baseline: 1.0448x; 1.0448x over previous
//
#include <hip/hip_runtime.h>
#include <hip/hip_bf16.h>
#include <math.h>

// Problem dims
#define BATCH 8192
#define INF   1024
#define LEAFW 256
#define OUTF  1024
#define NLEAF 16
#define NNODE 15
#define NTOT  4096      // NLEAF * LEAFW
#define KEXT  4160      // 4096 + 64 (mixture @ B2 folded into GEMM2's K)

typedef __bf16 bf16;
typedef __bf16 bf16x4 __attribute__((ext_vector_type(4)));
typedef __bf16 bf16x8 __attribute__((ext_vector_type(8)));
typedef float  f32x4  __attribute__((ext_vector_type(4)));

// GEMM tile config (m97-style: 128x128 tile, BK=64, 4 waves of 4x4 16x16x32)
#define BM 128
#define BN 128
#define BK 64

// ---------------------------------------------------------------------------
// Fused weight prep, one flat grid of 256-thread blocks:
//   blocks [0,4096):    w1s[l][f][h] fp32 -> W1T[l*256+h][f] bf16 (ld=1024)
//   blocks [4096,8192): w2s[l][h][o] fp32 -> W2T[o][l*256+h] bf16 (ld=KEXT)
//   blocks [8192,8448): W2T cols 4096..4159 = b2s^T | 0
__global__ __launch_bounds__(256) void prep_weights_kernel(
    const float* __restrict__ w1, const float* __restrict__ w2,
    const float* __restrict__ b2s, bf16* __restrict__ W1T,
    bf16* __restrict__ W2T) {
  __shared__ float tile[32][33];
  int b  = blockIdx.x;
  int t  = threadIdx.x;
  int tx = t & 31, ty = t >> 5;  // (32, 8)

  if (b < 4096) {  // w1 transpose
    int l = b >> 8, rem = b & 255;
    int hb = (rem & 7) * 32, fb = (rem >> 3) * 32;
    const float* in1 = w1 + (size_t)l * INF * LEAFW;
#pragma unroll
    for (int i = 0; i < 4; ++i)
      tile[ty + 8 * i][tx] = in1[(size_t)(fb + ty + 8 * i) * LEAFW + hb + tx];
    __syncthreads();
#pragma unroll
    for (int i = 0; i < 4; ++i)
      W1T[(size_t)(l * LEAFW + hb + ty + 8 * i) * INF + fb + tx] =
          (bf16)tile[tx][ty + 8 * i];
  } else if (b < 8192) {  // w2 transpose
    int bb = b - 4096;
    int l = bb >> 8, rem = bb & 255;
    int ob = (rem & 31) * 32, hb = (rem >> 5) * 32;
    const float* in2 = w2 + (size_t)l * LEAFW * OUTF;
#pragma unroll
    for (int i = 0; i < 4; ++i)
      tile[ty + 8 * i][tx] = in2[(size_t)(hb + ty + 8 * i) * OUTF + ob + tx];
    __syncthreads();
#pragma unroll
    for (int i = 0; i < 4; ++i)
      W2T[(size_t)(ob + ty + 8 * i) * KEXT + l * LEAFW + hb + tx] =
          (bf16)tile[tx][ty + 8 * i];
  } else {  // W2T extension columns
    int i = (b - 8192) * 256 + t;  // < 1024*64
    int o = i >> 6, j = i & 63;
    W2T[(size_t)o * KEXT + NTOT + j] =
        (j < NLEAF) ? (bf16)b2s[(size_t)j * OUTF + o] : (bf16)0.f;
  }
}

// ---------------------------------------------------------------------------
// Fused gating + x->bf16 convert. One wave per row: float4 loads, 15 fp32
// dot products, butterfly reduce, sigmoid, tree product -> mg[row][16];
// writes Xbf row (bf16) from the same registers; writes mixture (bf16) into
// Aact cols 4096..4111 and zeros cols 4112..4159.
__global__ __launch_bounds__(256) void gating_kernel(
    const float4* __restrict__ x4, const float4* __restrict__ nw4,
    const float* __restrict__ nb, float* __restrict__ mg,
    bf16* __restrict__ Aact, bf16x4* __restrict__ Xbf4) {
  int row  = blockIdx.x * 4 + (threadIdx.x >> 6);
  int lane = threadIdx.x & 63;
  const float4* xr4 = x4 + (size_t)row * (INF / 4);

  float p[NNODE];
#pragma unroll
  for (int j = 0; j < NNODE; ++j) p[j] = 0.f;
#pragma unroll
  for (int c = 0; c < INF / 256; ++c) {  // 4 iters, float4 per lane
    int idx = c * 64 + lane;
    float4 xv = xr4[idx];
#pragma unroll
    for (int j = 0; j < NNODE; ++j) {
      float4 wv = nw4[j * (INF / 4) + idx];
      p[j] += xv.x * wv.x + xv.y * wv.y + xv.z * wv.z + xv.w * wv.w;
    }
    bf16x4 o = {(bf16)xv.x, (bf16)xv.y, (bf16)xv.z, (bf16)xv.w};
    Xbf4[(size_t)row * (INF / 4) + idx] = o;
  }
  // butterfly reduce: every lane ends with the full sum for every node
#pragma unroll
  for (int j = 0; j < NNODE; ++j) {
    float v = p[j];
#pragma unroll
    for (int off = 32; off > 0; off >>= 1) v += __shfl_xor(v, off);
    p[j] = 1.f / (1.f + expf(-(v + nb[j])));  // sigmoid
  }
  // mixture for all 16 leaves (wave-uniform, static indices only)
  float mixv[NLEAF];
#pragma unroll
  for (int L = 0; L < NLEAF; ++L) {
    int n1 = 1 + (L >> 3), n2 = 3 + (L >> 2), n3 = 7 + (L >> 1);
    float m = ((L >> 3) & 1) ? p[0] : (1.f - p[0]);
    m *= ((L >> 2) & 1) ? p[n1] : (1.f - p[n1]);
    m *= ((L >> 1) & 1) ? p[n2] : (1.f - p[n2]);
    m *= (L & 1) ? p[n3] : (1.f - p[n3]);
    mixv[L] = m;
  }
  bf16* arow = Aact + (size_t)row * KEXT + NTOT;
  if (lane == 0) {
#pragma unroll
    for (int L = 0; L < NLEAF; ++L) {
      mg[row * NLEAF + L] = mixv[L];
      arow[L] = (bf16)mixv[L];
    }
  }
  if (lane >= 16) arow[lane] = (bf16)0.f;  // cols 4112..4159
}

// ---------------------------------------------------------------------------
// bf16 MFMA GEMM: C[M][N] = A[M][K] (row-major, lda) @ BT[N][K]^T (row-major,
// ldb). 128x128 tile, BK=64, global_load_lds width-16 staging with XOR chunk
// swizzle (coalesced global reads + conflict-free ds_read_b128).
// EPI=0: v = relu(acc + bias[col]) * mg[row][col>>8], store bf16 to outB.
// EPI=1: store fp32 acc to outF.
template <int EPI>
__global__ __launch_bounds__(256, 2) void gemm_kernel(
    const bf16* __restrict__ A, int lda, const bf16* __restrict__ BT, int ldb,
    int K, const float* __restrict__ bias, const float* __restrict__ mg,
    bf16* __restrict__ outB, int ldob, float* __restrict__ outF, int ldof) {
  __shared__ __align__(16) bf16 As[BM * BK];
  __shared__ __align__(16) bf16 Bs[BN * BK];

  int t    = threadIdx.x;
  int lane = t & 63;
  int w    = t >> 6;
  int bm   = blockIdx.x * BM;
  int bn   = blockIdx.y * BN;
  int wm   = (w >> 1) * 64;
  int wn   = (w & 1) * 64;

  int sr = t >> 3;                  // staging row-within-issue (0..31)
  int sc = t & 7;                   // staging chunk (0..7)
  int gc = ((sc ^ (sr & 7)) << 3);  // swizzled global col offset (elems)

  f32x4 acc[4][4];
#pragma unroll
  for (int i = 0; i < 4; ++i)
#pragma unroll
    for (int j = 0; j < 4; ++j) acc[i][j] = (f32x4){0.f, 0.f, 0.f, 0.f};

  for (int k0 = 0; k0 < K; k0 += BK) {
#pragma unroll
    for (int i = 0; i < 4; ++i) {
      int r = i * 32 + sr;
      __builtin_amdgcn_global_load_lds(
          (const __attribute__((address_space(1))) void*)(
              A + (size_t)(bm + r) * lda + k0 + gc),
          (__attribute__((address_space(3))) void*)((char*)As + i * 4096 +
                                                    t * 16),
          16, 0, 0);
    }
#pragma unroll
    for (int i = 0; i < 4; ++i) {
      int r = i * 32 + sr;
      __builtin_amdgcn_global_load_lds(
          (const __attribute__((address_space(1))) void*)(
              BT + (size_t)(bn + r) * ldb + k0 + gc),
          (__attribute__((address_space(3))) void*)((char*)Bs + i * 4096 +
                                                    t * 16),
          16, 0, 0);
    }
    __syncthreads();

#pragma unroll
    for (int kk = 0; kk < 2; ++kk) {
      int c = (kk * 4 + (lane >> 4)) ^ (lane & 7);  // swizzled chunk
      bf16x8 af[4], bfr[4];
#pragma unroll
      for (int i = 0; i < 4; ++i) {
        int R = wm + i * 16 + (lane & 15);
        af[i] = *reinterpret_cast<const bf16x8*>(&As[R * 64 + c * 8]);
      }
#pragma unroll
      for (int j = 0; j < 4; ++j) {
        int R = wn + j * 16 + (lane & 15);
        bfr[j] = *reinterpret_cast<const bf16x8*>(&Bs[R * 64 + c * 8]);
      }
#pragma unroll
      for (int i = 0; i < 4; ++i)
#pragma unroll
        for (int j = 0; j < 4; ++j)
          acc[i][j] = __builtin_amdgcn_mfma_f32_16x16x32_bf16(
              af[i], bfr[j], acc[i][j], 0, 0, 0);
    }
    __syncthreads();
  }

  // Epilogue. C/D layout (m89-verified): col = lane&15, row = (lane>>4)*4+reg
  int r0 = bm + wm + ((lane >> 4) << 2);
  int c0 = bn + wn + (lane & 15);
  if (EPI == 0) {
    int leaf = (bn + wn) >> 8;  // wave-uniform: 64-col span within 256 block
#pragma unroll
    for (int i = 0; i < 4; ++i) {
#pragma unroll
      for (int r = 0; r < 4; ++r) {
        int row = r0 + i * 16 + r;
        float g = mg[row * NLEAF + leaf];
#pragma unroll
        for (int j = 0; j < 4; ++j) {
          int col = c0 + j * 16;
          float v = acc[i][j][r] + bias[col];
          v = v > 0.f ? v : 0.f;
          outB[(size_t)row * ldob + col] = (bf16)(v * g);
        }
      }
    }
  } else {
#pragma unroll
    for (int i = 0; i < 4; ++i)
#pragma unroll
      for (int r = 0; r < 4; ++r) {
        int row = r0 + i * 16 + r;
#pragma unroll
        for (int j = 0; j < 4; ++j)
          outF[(size_t)row * ldof + (c0 + j * 16)] = acc[i][j][r];
      }
  }
}

// ---------------------------------------------------------------------------
extern "C" void kernel_launch(void* const* d_in, const int* in_sizes, int n_in,
                              void* d_out, int out_size, void* d_ws,
                              size_t ws_size, hipStream_t stream) {
  const float* x   = (const float*)d_in[0];  // [8192][1024]
  const float* nw  = (const float*)d_in[1];  // [15][1024]
  const float* nb  = (const float*)d_in[2];  // [15]
  const float* w1s = (const float*)d_in[3];  // [16][1024][256]
  const float* b1s = (const float*)d_in[4];  // [16][256] -> flat [4096]
  const float* w2s = (const float*)d_in[5];  // [16][256][1024]
  const float* b2s = (const float*)d_in[6];  // [16][1024]
  float* out = (float*)d_out;                // [8192][1024]

  char* ws = (char*)d_ws;
  bf16*  Xbf  = (bf16*)(ws);                  // 16,777,216 B
  bf16*  W1T  = (bf16*)(ws + 16777216);       //  8,388,608 B  [4096][1024]
  bf16*  W2T  = (bf16*)(ws + 25165824);       //  8,519,680 B  [1024][4160]
  float* mg   = (float*)(ws + 33685504);      //    524,288 B  [8192][16]
  bf16*  Aact = (bf16*)(ws + 34209792);       // 68,157,440 B  [8192][4160]

  prep_weights_kernel<<<dim3(8448), 256, 0, stream>>>(w1s, w2s, b2s, W1T, W2T);
  gating_kernel<<<dim3(BATCH / 4), 256, 0, stream>>>(
      (const float4*)x, (const float4*)nw, nb, mg, Aact, (bf16x4*)Xbf);

  // GEMM1: Aact[:, :4096] = relu(Xbf @ W1T^T + b1) * mixture
  gemm_kernel<0><<<dim3(BATCH / BM, NTOT / BN), 256, 0, stream>>>(
      Xbf, INF, W1T, INF, INF, b1s, mg, Aact, KEXT, nullptr, 0);
  // GEMM2: out = Aact @ W2T^T   (K = 4160 includes mixture @ B2 term)
  gemm_kernel<1><<<dim3(BATCH / BM, OUTF / BN), 256, 0, stream>>>(
      Aact, KEXT, W2T, KEXT, KEXT, nullptr, nullptr, nullptr, 0, out, OUTF);
}